// Round 2
// baseline (910.147 us; speedup 1.0000x reference)
//
#include <hip/hip_runtime.h>

// AVNN Type1 Conv2d fused kernel, MI355X (gfx950).
//
//   act = relu(Wx · a + bx);  r = a*y/(|a|+eps);  car = Wy · r + by
//   x: [B=8][C=128][H*W=65536][2] fp32 (a=idx0, y=idx1), out: [B][O=128][HW][2]
//
// Strategy: memory-bound (1.07 GB traffic ~170us floor). GEMMs done with
// bf16x2-split MFMA (hi/lo, 3 passes) for fp32-class accuracy at ~41us of
// matrix pipe. Per block: 8 waves, 64-pixel tile, all 128 o. Weights as
// per-wave register fragments (64 VGPR). Values staged in LDS bf16 arrays
// [p][c] with XOR swizzle ((p&7)<<4) for conflict-free ds_read_b128 frags.
// Double-buffered LDS + issue-early/write-late staging (T14).
// R1: + nontemporal loads/stores (x read once, out written once — keep the
//     streaming traffic out of L2/L3). No structural change (no counter data
//     yet; both prior rounds failed on GPU acquisition).

#define CC 128
#define HW 65536
#define OO 128
#define EPSF 1e-6f
#define TILE_P 64
#define TPB 8  // tiles per block; grid = 8192/TPB = 1024 blocks

typedef __attribute__((ext_vector_type(8))) short bf16x8;
typedef __attribute__((ext_vector_type(4))) float f32x4;
typedef __attribute__((ext_vector_type(2))) float f32x2;

__device__ __forceinline__ unsigned int f2bf(float f) {
  unsigned int u = __float_as_uint(f);
  return (u + 0x7FFFu + ((u >> 16) & 1u)) >> 16;  // RNE
}
__device__ __forceinline__ float bf2f(unsigned int h) {
  return __uint_as_float(h << 16);
}

// Convert 16 staged (a,y) float2 for channels cb..cb+15 at pixel=lane into
// 4 bf16 LDS arrays (act_hi, act_lo, r_hi, r_lo), XOR-swizzled b64 writes.
__device__ __forceinline__ void stage_write(const f32x2* v, unsigned char* wb,
                                            int lane, int cb) {
#pragma unroll
  for (int g = 0; g < 4; ++g) {
    unsigned int aw0 = 0, aw1 = 0, lw0 = 0, lw1 = 0;
    unsigned int rw0 = 0, rw1 = 0, sw0 = 0, sw1 = 0;
#pragma unroll
    for (int j = 0; j < 4; ++j) {
      float a = v[g * 4 + j].x;
      float yv = v[g * 4 + j].y;
      float r = a * yv / (fabsf(a) + EPSF);
      unsigned int ah = f2bf(a);
      unsigned int al = f2bf(a - bf2f(ah));
      unsigned int rh = f2bf(r);
      unsigned int rl = f2bf(r - bf2f(rh));
      int sh = (j & 1) * 16;
      if (j < 2) {
        aw0 |= ah << sh; lw0 |= al << sh; rw0 |= rh << sh; sw0 |= rl << sh;
      } else {
        aw1 |= ah << sh; lw1 |= al << sh; rw1 |= rh << sh; sw1 |= rl << sh;
      }
    }
    const int c0 = cb + g * 4;
    const int off = (lane << 8) + (((c0 << 1)) ^ ((lane & 7) << 4));
    uint2 t;
    t.x = aw0; t.y = aw1; *(uint2*)(wb + off) = t;
    t.x = lw0; t.y = lw1; *(uint2*)(wb + 16384 + off) = t;
    t.x = rw0; t.y = rw1; *(uint2*)(wb + 32768 + off) = t;
    t.x = sw0; t.y = sw1; *(uint2*)(wb + 49152 + off) = t;
  }
}

__global__ __launch_bounds__(512) void avnn_kernel(
    const float* __restrict__ x, const float* __restrict__ wxg,
    const float* __restrict__ bxg, const float* __restrict__ wyg,
    const float* __restrict__ byg, float* __restrict__ out) {
  // 2 buffers x 4 arrays x (64p x 128c) bf16 = 128 KiB
  __shared__ unsigned char lds[2 * 4 * 64 * 256];

  const int tid = threadIdx.x;
  const int lane = tid & 63;
  const int wid = tid >> 6;  // 8 waves
  const int lm = lane & 15;
  const int lg = lane >> 4;

  // ---- per-wave weight fragments: o rows [o0, o0+16), all 128 c ----
  const int o0 = wid * 16;
  bf16x8 wxh[4], wxl[4], wyh[4], wyl[4];
#pragma unroll
  for (int kk = 0; kk < 4; ++kk) {
    const int row = o0 + lm;
    const int c0 = kk * 32 + lg * 8;
    const float* px = wxg + row * CC + c0;
    const float* py = wyg + row * CC + c0;
#pragma unroll
    for (int j = 0; j < 8; ++j) {
      float f = px[j];
      unsigned int h = f2bf(f);
      wxh[kk][j] = (short)h;
      wxl[kk][j] = (short)f2bf(f - bf2f(h));
      float g = py[j];
      unsigned int h2 = f2bf(g);
      wyh[kk][j] = (short)h2;
      wyl[kk][j] = (short)f2bf(g - bf2f(h2));
    }
  }
  float bxr[4], byr[4];
#pragma unroll
  for (int r = 0; r < 4; ++r) {
    bxr[r] = bxg[o0 + lg * 4 + r];
    byr[r] = byg[o0 + lg * 4 + r];
  }

  // ---- tile iteration: TPB consecutive 64-pixel tiles in one image b ----
  const int tile0 = blockIdx.x * TPB;
  const int b = tile0 >> 10;                 // 1024 tiles per image
  const int pbase = (tile0 & 1023) * TILE_P; // first pixel of first tile
  const f32x2* xp = (const f32x2*)x + (size_t)(b * CC) * HW;
  f32x2* op = (f32x2*)out + (size_t)(b * OO) * HW;
  const int cb = wid * 16;  // this wave stages channels cb..cb+15

  // prologue: stage tile 0 into buf 0
  {
    f32x2 v[16];
#pragma unroll
    for (int i = 0; i < 16; ++i)
      v[i] = __builtin_nontemporal_load(&xp[(size_t)(cb + i) * HW + pbase + lane]);
    stage_write(v, lds, lane, cb);
  }
  __syncthreads();

#pragma unroll 1
  for (int t = 0; t < TPB; ++t) {
    const int p0 = pbase + t * TILE_P;
    const bool more = (t + 1 < TPB);

    // T14 issue-early: next tile's global loads in flight during MFMA
    f32x2 vn[16];
    if (more) {
#pragma unroll
      for (int i = 0; i < 16; ++i)
        vn[i] = __builtin_nontemporal_load(
            &xp[(size_t)(cb + i) * HW + p0 + TILE_P + lane]);
    }

    // ---- compute tile t from buf (t&1) ----
    const unsigned char* rb = lds + (t & 1) * 65536;
    f32x4 ax[4], ay[4];
#pragma unroll
    for (int np = 0; np < 4; ++np) {
      ax[np] = (f32x4){0.f, 0.f, 0.f, 0.f};
      ay[np] = (f32x4){0.f, 0.f, 0.f, 0.f};
    }
#pragma unroll
    for (int kk = 0; kk < 4; ++kk) {
#pragma unroll
      for (int np = 0; np < 4; ++np) {
        const int p = np * 16 + lm;
        const int c0 = kk * 32 + lg * 8;
        const int off = (p << 8) + (((c0 << 1)) ^ ((p & 7) << 4));
        bf16x8 bah = *(const bf16x8*)(rb + off);
        bf16x8 bal = *(const bf16x8*)(rb + 16384 + off);
        bf16x8 brh = *(const bf16x8*)(rb + 32768 + off);
        bf16x8 brl = *(const bf16x8*)(rb + 49152 + off);
        ax[np] = __builtin_amdgcn_mfma_f32_16x16x32_bf16(wxh[kk], bah, ax[np], 0, 0, 0);
        ax[np] = __builtin_amdgcn_mfma_f32_16x16x32_bf16(wxl[kk], bah, ax[np], 0, 0, 0);
        ax[np] = __builtin_amdgcn_mfma_f32_16x16x32_bf16(wxh[kk], bal, ax[np], 0, 0, 0);
        ay[np] = __builtin_amdgcn_mfma_f32_16x16x32_bf16(wyh[kk], brh, ay[np], 0, 0, 0);
        ay[np] = __builtin_amdgcn_mfma_f32_16x16x32_bf16(wyl[kk], brh, ay[np], 0, 0, 0);
        ay[np] = __builtin_amdgcn_mfma_f32_16x16x32_bf16(wyh[kk], brl, ay[np], 0, 0, 0);
      }
    }

    // ---- epilogue: bias + relu, interleaved float2 store (nontemporal) ----
#pragma unroll
    for (int np = 0; np < 4; ++np) {
#pragma unroll
      for (int r = 0; r < 4; ++r) {
        const int o = o0 + lg * 4 + r;
        const int p = p0 + np * 16 + lm;
        f32x2 o2;
        o2.x = fmaxf(ax[np][r] + bxr[r], 0.0f);
        o2.y = ay[np][r] + byr[r];
        __builtin_nontemporal_store(o2, &op[(size_t)o * HW + p]);
      }
    }

    // T14 write-late: convert + LDS-write next tile into buf ((t+1)&1)
    if (more) stage_write(vn, lds + ((t + 1) & 1) * 65536, lane, cb);
    __syncthreads();
  }
}

extern "C" void kernel_launch(void* const* d_in, const int* in_sizes, int n_in,
                              void* d_out, int out_size, void* d_ws, size_t ws_size,
                              hipStream_t stream) {
  const float* x = (const float*)d_in[0];
  const float* wx = (const float*)d_in[1];
  const float* bx = (const float*)d_in[2];
  const float* wy = (const float*)d_in[3];
  const float* by = (const float*)d_in[4];
  float* out = (float*)d_out;
  // 8 images * 1024 tiles = 8192 tiles; TPB=8 tiles/block -> 1024 blocks
  dim3 grid(1024);
  dim3 block(512);
  hipLaunchKernelGGL(avnn_kernel, grid, block, 0, stream, x, wx, bx, wy, by, out);
}